// Round 16
// baseline (174.668 us; speedup 1.0000x reference)
//
#include <hip/hip_runtime.h>

typedef unsigned short u16;
typedef unsigned int u32;
typedef u16 u16x4 __attribute__((ext_vector_type(4)));
typedef u16 u16x8 __attribute__((ext_vector_type(8)));
typedef u32 u32x4 __attribute__((ext_vector_type(4)));
typedef __bf16 bf16x8 __attribute__((ext_vector_type(8)));
typedef float f32x4 __attribute__((ext_vector_type(4)));

#define GPTR(p) (const __attribute__((address_space(1))) void*)(p)
#define LPTR(p) (__attribute__((address_space(3))) void*)(p)
// async global->LDS, 16B per lane; LDS dest = wave-uniform base + lane*16
#define ASYNC16(g, l) __builtin_amdgcn_global_load_lds(GPTR(g), LPTR(l), 16, 0, 0)

// raw v_exp_f32 (no denormal-range fixup; inputs here are |x| < 40)
#if __has_builtin(__builtin_amdgcn_exp2f)
#define EXP2(x) __builtin_amdgcn_exp2f(x)
#else
#define EXP2(x) __builtin_exp2f(x)
#endif

// fp32 -> bf16 RTNE (epilogue / non-hot paths)
__device__ __forceinline__ u16 f2bf(float f) {
    u32 u = __builtin_bit_cast(u32, f);
    return (u16)((u + 0x7fffu + ((u >> 16) & 1u)) >> 16);
}
__device__ __forceinline__ bf16x8 ld8(const void* p) {
    return __builtin_bit_cast(bf16x8, *(const u16x8*)p);
}

// ---------------- weights fp32 -> bf16 (query converts inside gemm0) ----------
// 4096 blocks: [0,1024) Wq, [1024,2048) Wk, [2048,3072) Wv, [3072,4096) Wo
__global__ void cvt_w(const float* __restrict__ wq, const float* __restrict__ wk,
                      const float* __restrict__ wv, const float* __restrict__ wo,
                      u16* __restrict__ wcat, u16* __restrict__ wob) {
    const int t = blockIdx.x;
    const int w = t >> 10;
    const size_t base = (size_t)(t & 1023) * 256;
    const float* src = (w == 0) ? wq : (w == 1) ? wk : (w == 2) ? wv : wo;
    u16* dst = (w == 0) ? wcat : (w == 1) ? wcat + 1024 * 1024
             : (w == 2) ? wcat + 2 * 1024 * 1024 : wob;
    const size_t i = base + threadIdx.x;
    float4 v = ((const float4*)src)[i];
    ushort4 o4;
    o4.x = f2bf(v.x); o4.y = f2bf(v.y); o4.z = f2bf(v.z); o4.w = f2bf(v.w);
    ((ushort4*)dst)[i] = o4;
}

// ---------------- GEMM: C[m][n] = sum_k A[m][k]*B[n][k]  (B^T input) ----------
// BK=64, XOR-swizzled LDS tiles (128B rows), XCD-chunked block swizzle.
// MODE 0: A is FP32 (raw query) -> reg-staged with v_cvt_pk_bf16_f32 (RTNE,
//   bit-identical to the old cvt pass) + swizzled ds_write_b128; deletes the
//   50 MB query-conversion round-trip.  B stays global_load_lds (pre-swizzled
//   source).  Issue order: A f32 loads -> B ASYNC16 -> cvt (waits vmcnt(4),
//   B stays in flight) -> ds_write -> barrier.
//   N=3072; Q,K -> [b][h][s][64]; V -> TRANSPOSED [b][h][64][s].
// MODE 1: A is bf16 (X2); both operands via ASYNC16.  OF = C + b0[n] (fp32).
template<int MODE>
__global__ __launch_bounds__(256, 4) void gemm_bt(
    const void* __restrict__ Av, const u16* __restrict__ B,
    const float* __restrict__ b0, const float* __restrict__ b1, const float* __restrict__ b2,
    u16* __restrict__ O0, u16* __restrict__ O1, u16* __restrict__ O2,
    float* __restrict__ OF)
{
    constexpr int K = 1024;
    constexpr int NBLK = (MODE == 0) ? 24 : 8;     // n-blocks per row
    constexpr int CPX  = (MODE == 0) ? 192 : 64;   // nwg / 8
    __shared__ __align__(16) u16 As[128 * 64];
    __shared__ __align__(16) u16 Bs[128 * 64];
    const int tid = threadIdx.x;
    const int wave = tid >> 6, lane = tid & 63;
    const int lin = blockIdx.y * (int)gridDim.x + blockIdx.x;   // dispatch order
    const int nl = (lin & 7) * CPX + (lin >> 3);                // bijective remap
    const int m0 = (nl / NBLK) * 128, n0 = (nl % NBLK) * 128;
    const int wm = (wave >> 1) * 64, wn = (wave & 1) * 64;
    const int fr = lane & 15, fg = lane >> 4;

    f32x4 acc[4][4] = {};

    // staging: 8 rows per 128B-row group (8 lanes x 16B)
    const int srow = lane >> 3;
    const int sw = (((lane & 7) ^ srow) << 4);   // swizzled byte offset in row
    // fragment-read byte cols (swizzled), per half
    const int rdo0 = (fg * 16) ^ ((fr & 7) << 4);
    const int rdo1 = (64 + fg * 16) ^ ((fr & 7) << 4);

    for (int kt = 0; kt < K; kt += 64) {
        if constexpr (MODE == 0) {
            const float* Af = (const float*)Av;
            // 1) issue A f32 loads (8x dwordx4)
            float4 va[4][2];
            #pragma unroll
            for (int j = 0; j < 4; ++j) {
                const float* ap = Af + (size_t)(m0 + wave * 32 + j * 8 + srow) * K
                                  + kt + (lane & 7) * 8;
                va[j][0] = *(const float4*)ap;
                va[j][1] = *(const float4*)(ap + 4);
            }
            // 2) issue B ASYNC16 (stays in flight during cvt)
            #pragma unroll
            for (int j = 0; j < 4; ++j) {
                const int row = wave * 32 + j * 8;
                ASYNC16((const char*)(B + (size_t)(n0 + row + srow) * K + kt) + sw,
                        (char*)Bs + row * 128);
            }
            // 3) cvt + swizzled ds_write (RTNE, bit-identical to f2bf)
            #pragma unroll
            for (int j = 0; j < 4; ++j) {
                u32 p0, p1, p2, p3;
                asm("v_cvt_pk_bf16_f32 %0, %1, %2" : "=v"(p0) : "v"(va[j][0].x), "v"(va[j][0].y));
                asm("v_cvt_pk_bf16_f32 %0, %1, %2" : "=v"(p1) : "v"(va[j][0].z), "v"(va[j][0].w));
                asm("v_cvt_pk_bf16_f32 %0, %1, %2" : "=v"(p2) : "v"(va[j][1].x), "v"(va[j][1].y));
                asm("v_cvt_pk_bf16_f32 %0, %1, %2" : "=v"(p3) : "v"(va[j][1].z), "v"(va[j][1].w));
                *(u32x4*)((char*)As + (wave * 32 + j * 8 + srow) * 128 + sw) =
                    u32x4{p0, p1, p2, p3};
            }
        } else {
            const u16* Aw = (const u16*)Av;
            #pragma unroll
            for (int j = 0; j < 4; ++j) {
                const int row = wave * 32 + j * 8;
                ASYNC16((const char*)(Aw + (size_t)(m0 + row + srow) * K + kt) + sw,
                        (char*)As + row * 128);
                ASYNC16((const char*)(B + (size_t)(n0 + row + srow) * K + kt) + sw,
                        (char*)Bs + row * 128);
            }
        }
        __syncthreads();
        #pragma unroll
        for (int half = 0; half < 2; ++half) {
            const int co = half ? rdo1 : rdo0;
            bf16x8 af[4], bfv[4];
            #pragma unroll
            for (int i = 0; i < 4; ++i) af[i]  = ld8((const char*)As + (wm + i * 16 + fr) * 128 + co);
            #pragma unroll
            for (int j = 0; j < 4; ++j) bfv[j] = ld8((const char*)Bs + (wn + j * 16 + fr) * 128 + co);
            #pragma unroll
            for (int i = 0; i < 4; ++i)
                #pragma unroll
                for (int j = 0; j < 4; ++j)
                    acc[i][j] = __builtin_amdgcn_mfma_f32_16x16x32_bf16(af[i], bfv[j], acc[i][j], 0, 0, 0);
        }
        __syncthreads();
    }

    if constexpr (MODE == 0) {
        const float QSCALE = 0.125f * 1.44269504f;   // 1/sqrt(64) * log2(e)
        #pragma unroll
        for (int j = 0; j < 4; ++j) {
            const int n = n0 + wn + j * 16 + fr;
            const int sel = n >> 10;          // 0=Q 1=K 2=V (uniform per fragment)
            const int w = n & 1023;
            const float bb = (sel == 0 ? b0 : sel == 1 ? b1 : b2)[w];
            const int h = w >> 6, d = w & 63;
            if (sel == 2) {
                // V transposed: Vt[(bi*16+h)*64 + d][s], s-consecutive -> u16x4
                #pragma unroll
                for (int i = 0; i < 4; ++i) {
                    const int m = m0 + wm + i * 16 + fg * 4;   // s base (4-aligned)
                    u16x4 st;
                    #pragma unroll
                    for (int r = 0; r < 4; ++r) st[r] = f2bf(acc[i][j][r] + bb);
                    *(u16x4*)&O2[((size_t)(((m >> 11) * 16 + h) * 64 + d)) * 2048 + (m & 2047)] = st;
                }
            } else {
                const float scale = (sel == 0) ? QSCALE : 1.0f;
                u16* const dst = (sel == 0 ? O0 : O1);
                #pragma unroll
                for (int i = 0; i < 4; ++i) {
                    #pragma unroll
                    for (int r = 0; r < 4; ++r) {
                        const int m = m0 + wm + i * 16 + fg * 4 + r;
                        dst[(((size_t)((m >> 11) * 16 + h) * 2048 + (m & 2047)) << 6) + d] =
                            f2bf((acc[i][j][r] + bb) * scale);
                    }
                }
            }
        }
    } else {
        #pragma unroll
        for (int j = 0; j < 4; ++j) {
            const int n = n0 + wn + j * 16 + fr;
            const float bb = b0[n];
            #pragma unroll
            for (int i = 0; i < 4; ++i) {
                #pragma unroll
                for (int r = 0; r < 4; ++r) {
                    const int m = m0 + wm + i * 16 + fg * 4 + r;
                    OF[(size_t)m * 1024 + n] = acc[i][j][r] + bb;
                }
            }
        }
    }
}

// ---------------- attention kv-loop body, QROWS=64/wave -----------------------
// K/V LDS-staged (fetch-once shared by 4 waves); K/V fragment reads are
// qs-invariant -> 64 q-rows/wave amortizes each ds_read over 2x the MFMA work.
template<bool MASKED>
__device__ __forceinline__ void kv_loop(
    char* smem, const u16* __restrict__ Kbh, const u16* __restrict__ Vtbh,
    const float* __restrict__ mrow, int wave, int fg, int a0, int a1, int t0,
    int srow, int scb, bf16x8 (&qf)[4][2], f32x4 (&o)[4][4], f32x4 (&den)[4],
    const f32x4& FZ, const bf16x8& ONES)
{
    auto STAGE = [&](int buf, int kv0) {
        #pragma unroll
        for (int j = 0; j < 2; ++j) {
            const int r0 = wave * 16 + j * 8;
            const int row = r0 + srow;
            const int sw = scb ^ ((row & 7) << 4);
            ASYNC16((const char*)(Kbh + (size_t)(kv0 + row) * 64) + sw,
                    smem + buf * 8192 + r0 * 128);
            ASYNC16((const char*)(Vtbh + (size_t)row * 2048 + kv0) + sw,
                    smem + 16384 + buf * 8192 + r0 * 128);
        }
    };

    STAGE(0, t0 * 64);
    for (int it = 0; it < 32; it += 2) {
        #pragma unroll
        for (int half = 0; half < 2; ++half) {
            const int tile = (t0 + it + half) & 31;
            const int kv = tile * 64;
            const int kb = half * 8192;            // compile-time dbuf bases
            const int vb = 16384 + half * 8192;
            __syncthreads();                        // buf[half] staged
            if (it + half < 31) STAGE(half ^ 1, ((tile + 1) & 31) * 64);

            float4 mv[4];
            if (MASKED) {
                #pragma unroll
                for (int nj = 0; nj < 4; ++nj)
                    mv[nj] = *(const float4*)(mrow + kv + nj * 16 + fg * 4);
            }

            // per 32-key half: QK -> softmax -> in-reg transpose -> PV
            #pragma unroll
            for (int hh = 0; hh < 2; ++hh) {
                const int aK = hh ? a1 : a0;        // V frag byte-half for this hh
                f32x4 s[2][4];
                #pragma unroll
                for (int njl = 0; njl < 2; ++njl) {
                    const int nj = hh * 2 + njl;
                    bf16x8 k0 = ld8(smem + kb + nj * 2048 + a0);
                    bf16x8 k1 = ld8(smem + kb + nj * 2048 + a1);
                    __builtin_amdgcn_s_setprio(1);
                    #pragma unroll
                    for (int qs = 0; qs < 4; ++qs) {
                        f32x4 z = __builtin_amdgcn_mfma_f32_16x16x32_bf16(k0, qf[qs][0], FZ, 0, 0, 0);
                        s[njl][qs] = __builtin_amdgcn_mfma_f32_16x16x32_bf16(k1, qf[qs][1], z, 0, 0, 0);
                    }
                    __builtin_amdgcn_s_setprio(0);
                }
                // softmax in place: p = exp2(s) [* mask]   (raw-rate v_exp_f32)
                #pragma unroll
                for (int njl = 0; njl < 2; ++njl) {
                    const int nj = hh * 2 + njl;
                    #pragma unroll
                    for (int qs = 0; qs < 4; ++qs)
                        #pragma unroll
                        for (int r = 0; r < 4; ++r) {
                            float p = EXP2(s[njl][qs][r]);
                            if (MASKED) p *= mv[nj][r];
                            s[njl][qs][r] = p;
                        }
                }
                // pack + 4x4 cross-lane transpose -> PV B-operand fragments
                bf16x8 pa[4];
                #pragma unroll
                for (int qs = 0; qs < 4; ++qs) {
                    u32 m0, m1, m2, m3;   // word (W1=njl, W0=r-pair)
                    asm("v_cvt_pk_bf16_f32 %0, %1, %2" : "=v"(m0) : "v"(s[0][qs][0]), "v"(s[0][qs][1]));
                    asm("v_cvt_pk_bf16_f32 %0, %1, %2" : "=v"(m1) : "v"(s[0][qs][2]), "v"(s[0][qs][3]));
                    asm("v_cvt_pk_bf16_f32 %0, %1, %2" : "=v"(m2) : "v"(s[1][qs][0]), "v"(s[1][qs][1]));
                    asm("v_cvt_pk_bf16_f32 %0, %1, %2" : "=v"(m3) : "v"(s[1][qs][2]), "v"(s[1][qs][3]));
                    // step 1: swap(L5, W1); step 2: swap(L4, W1)
                    asm("v_permlane32_swap_b32 %0, %1" : "+v"(m0), "+v"(m2));
                    asm("v_permlane32_swap_b32 %0, %1" : "+v"(m1), "+v"(m3));
                    asm("v_permlane16_swap_b32 %0, %1" : "+v"(m0), "+v"(m2));
                    asm("v_permlane16_swap_b32 %0, %1" : "+v"(m1), "+v"(m3));
                    pa[qs] = __builtin_bit_cast(bf16x8, u32x4{m0, m1, m2, m3});
                }

                // PV + MFMA denominator (row-sum with ONES A-operand)
                __builtin_amdgcn_s_setprio(1);
                #pragma unroll
                for (int qs = 0; qs < 4; ++qs)
                    den[qs] = __builtin_amdgcn_mfma_f32_16x16x32_bf16(ONES, pa[qs], den[qs], 0, 0, 0);
                #pragma unroll
                for (int dj = 0; dj < 4; ++dj) {
                    bf16x8 v = ld8(smem + vb + dj * 2048 + aK);
                    #pragma unroll
                    for (int qs = 0; qs < 4; ++qs)
                        o[dj][qs] = __builtin_amdgcn_mfma_f32_16x16x32_bf16(v, pa[qs], o[dj][qs], 0, 0, 0);
                }
                __builtin_amdgcn_s_setprio(0);
            }
        }
    }
}

// ---------------- flash attention: in-reg P, QROWS=64, mask fast-path ---------
// Q [bh][s][64] pre-scaled by 0.125*log2e, K [bh][s][64], Vt [bh][64][s],
// masks [b][s] fp32 (binary), out X2 [b][s][h*64+d] bf16.
// 4 waves x 64 q-rows = 256 q-rows/block; grid 512 (2 blocks/CU).
__global__ __launch_bounds__(256, 2) void attn_fwd(
    const u16* __restrict__ Qg, const u16* __restrict__ Kg, const u16* __restrict__ Vt,
    const float* __restrict__ masks, u16* __restrict__ X2)
{
    __shared__ __align__(16) char smem[32768];
    const int tid = threadIdx.x;
    const int wave = tid >> 6, lane = tid & 63;

    // bijective XCD swizzle: 512 wgs / 8 XCDs -> 64 contiguous wgs (8 bh) per XCD
    const int bidL = blockIdx.x;
    const int wg = ((bidL & 7) << 6) | (bidL >> 3);
    const int bh = wg >> 3;                        // 8 q-blocks per bh
    const int q0 = (wg & 7) * 256 + wave * 64;
    const int b = bh >> 4, h = bh & 15;
    const int fr = lane & 15, fg = lane >> 4;
    const int swz = (fr & 7) << 4;

    // loop-invariant LDS byte addresses
    const int a0 = fr * 128 + ((fg * 16) ^ swz);          // frag low 64B (k/d 0-31)
    const int a1 = fr * 128 + ((64 + fg * 16) ^ swz);     // frag high 64B

    const u16* const Kbh  = Kg + (size_t)bh * 2048 * 64;
    const u16* const Vtbh = Vt + (size_t)bh * 64 * 2048;
    const float* mrow = masks + b * 2048;

    // Q fragments (B-operand): 4 strips of 16 rows
    bf16x8 qf[4][2];
    #pragma unroll
    for (int qs = 0; qs < 4; ++qs) {
        const u16* qp = Qg + ((size_t)bh * 2048 + q0 + qs * 16 + fr) * 64 + fg * 8;
        qf[qs][0] = ld8(qp);
        qf[qs][1] = ld8(qp + 32);
    }

    // wave-uniform all-ones mask check (64 lanes x 8 float4 = 2048 values)
    bool ok = true;
    {
        const float4* mp = (const float4*)mrow;
        #pragma unroll
        for (int i = 0; i < 8; ++i) {
            float4 m = mp[lane + i * 64];
            ok = ok && (m.x == 1.0f) && (m.y == 1.0f) && (m.z == 1.0f) && (m.w == 1.0f);
        }
        ok = __all(ok);
    }

    f32x4 o[4][4] = {};                 // o[dj][qs]: d=dj*16+fg*4+r, q=qs*16+fr
    f32x4 den[4] = {};                  // softmax denominator (all 4 rows identical)
    const f32x4 FZ = {0.f, 0.f, 0.f, 0.f};                 // shared zero C-operand
    const u16x8 ONE_BITS = {0x3F80,0x3F80,0x3F80,0x3F80,0x3F80,0x3F80,0x3F80,0x3F80};
    const bf16x8 ONES = __builtin_bit_cast(bf16x8, ONE_BITS); // bf16 1.0 x8

    const int srow = lane >> 3;
    const int scb = (lane & 7) * 16;

    // co-resident blocks (p, p+256) start 16 tiles apart (key order commutes:
    // no-max softmax + linear denominator) -> pipe bursts interleave
    const int t0 = (((bidL >> 8) & 1) << 4);

    if (ok)
        kv_loop<false>(smem, Kbh, Vtbh, mrow, wave, fg, a0, a1, t0, srow, scb,
                       qf, o, den, FZ, ONES);
    else
        kv_loop<true>(smem, Kbh, Vtbh, mrow, wave, fg, a0, a1, t0, srow, scb,
                      qf, o, den, FZ, ONES);

    // normalize + store (den available in every lane; no cross-lane reduce)
    #pragma unroll
    for (int qs = 0; qs < 4; ++qs) {
        const float inv = 1.0f / den[qs][0];
        const int q = q0 + qs * 16 + fr;
        u16* dst = X2 + ((size_t)(b * 2048 + q)) * 1024 + h * 64 + fg * 4;
        #pragma unroll
        for (int dj = 0; dj < 4; ++dj) {
            u16x4 st;
            #pragma unroll
            for (int r = 0; r < 4; ++r) st[r] = f2bf(o[dj][qs][r] * inv);
            *(u16x4*)(dst + dj * 16) = st;
        }
    }
}

// ---------------- launch ----------------
extern "C" void kernel_launch(void* const* d_in, const int* in_sizes, int n_in,
                              void* d_out, int out_size, void* d_ws, size_t ws_size,
                              hipStream_t stream) {
    const float* query = (const float*)d_in[0];
    const float* masks = (const float*)d_in[1];
    const float* Wq = (const float*)d_in[2];
    const float* bq = (const float*)d_in[3];
    const float* Wk = (const float*)d_in[4];
    const float* bk = (const float*)d_in[5];
    const float* Wv = (const float*)d_in[6];
    const float* bv = (const float*)d_in[7];
    const float* Wo = (const float*)d_in[8];
    const float* bo = (const float*)d_in[9];
    float* out = (float*)d_out;

    // workspace (72 MB):
    //  [ 0,16M): X2 (attn out)
    //  [16,22M): Wcat  [22,24M): Wob
    //  [24,40M): Qg   [40,56M): Kg   [56,72M): Vt (written transposed by GEMM)
    char* ws = (char*)d_ws;
    u16* X2   = (u16*)(ws);
    u16* Wcat = (u16*)(ws + (16u << 20));
    u16* Wob  = (u16*)(ws + (22u << 20));
    u16* Qg   = (u16*)(ws + (24u << 20));
    u16* Kg   = (u16*)(ws + (40u << 20));
    u16* Vt   = (u16*)(ws + (56u << 20));

    cvt_w<<<4096, 256, 0, stream>>>(Wq, Wk, Wv, Wo, Wcat, Wob);
    gemm_bt<0><<<dim3(24, 64), 256, 0, stream>>>(query, Wcat, bq, bk, bv, Qg, Kg, Vt, nullptr);
    attn_fwd<<<512, 256, 0, stream>>>(Qg, Kg, Vt, masks, X2);
    gemm_bt<1><<<dim3(8, 64), 256, 0, stream>>>(X2, Wob, bo, nullptr, nullptr, nullptr,
                                                nullptr, nullptr, out);
}

// Round 17
// 166.367 us; speedup vs baseline: 1.0499x; 1.0499x over previous
//
#include <hip/hip_runtime.h>

typedef unsigned short u16;
typedef unsigned int u32;
typedef u16 u16x4 __attribute__((ext_vector_type(4)));
typedef u16 u16x8 __attribute__((ext_vector_type(8)));
typedef u32 u32x4 __attribute__((ext_vector_type(4)));
typedef __bf16 bf16x8 __attribute__((ext_vector_type(8)));
typedef float f32x4 __attribute__((ext_vector_type(4)));

#define GPTR(p) (const __attribute__((address_space(1))) void*)(p)
#define LPTR(p) (__attribute__((address_space(3))) void*)(p)
// async global->LDS, 16B per lane; LDS dest = wave-uniform base + lane*16
#define ASYNC16(g, l) __builtin_amdgcn_global_load_lds(GPTR(g), LPTR(l), 16, 0, 0)

// raw v_exp_f32 (no denormal-range fixup; inputs here are |x| < 40)
#if __has_builtin(__builtin_amdgcn_exp2f)
#define EXP2(x) __builtin_amdgcn_exp2f(x)
#else
#define EXP2(x) __builtin_exp2f(x)
#endif

// fp32 -> bf16 RTNE (epilogue / non-hot paths)
__device__ __forceinline__ u16 f2bf(float f) {
    u32 u = __builtin_bit_cast(u32, f);
    return (u16)((u + 0x7fffu + ((u >> 16) & 1u)) >> 16);
}
__device__ __forceinline__ bf16x8 ld8(const void* p) {
    return __builtin_bit_cast(bf16x8, *(const u16x8*)p);
}

// ---------------- fused fp32 -> bf16 conversion (single dispatch) -------------
// blocks [0,8192): query -> Xb;  [8192,+1024) each: Wq,Wk,Wv -> Wcat, Wo -> Wob
__global__ void cvt_all(const float* __restrict__ q,
                        const float* __restrict__ wq, const float* __restrict__ wk,
                        const float* __restrict__ wv, const float* __restrict__ wo,
                        u16* __restrict__ xb, u16* __restrict__ wcat, u16* __restrict__ wob) {
    const int blk = blockIdx.x;
    const float* src;
    u16* dst;
    size_t base;
    if (blk < 8192) {
        src = q; dst = xb; base = (size_t)blk * 256;
    } else {
        const int t = blk - 8192;
        const int w = t >> 10;
        base = (size_t)(t & 1023) * 256;
        src = (w == 0) ? wq : (w == 1) ? wk : (w == 2) ? wv : wo;
        dst = (w == 0) ? wcat : (w == 1) ? wcat + 1024 * 1024
            : (w == 2) ? wcat + 2 * 1024 * 1024 : wob;
    }
    const size_t i = base + threadIdx.x;
    float4 v = ((const float4*)src)[i];
    ushort4 o4;
    o4.x = f2bf(v.x); o4.y = f2bf(v.y); o4.z = f2bf(v.z); o4.w = f2bf(v.w);
    ((ushort4*)dst)[i] = o4;
}

// ---------------- GEMM: C[m][n] = sum_k A[m][k]*B[n][k]  (B^T input) ----------
// BK=64, XOR-swizzled LDS tiles (128B rows), XCD-chunked block swizzle.
// Per K-step: barrier (stage landed) -> ds_read ALL 16 b128 to regs ->
// barrier (lgkm drained) -> issue NEXT tile's ASYNC16 -> 32 MFMAs (prefetch
// flies under them).  Same barrier count as before, but the staging loads get
// a ~32-MFMA issue-to-use window instead of zero (attn-proven pattern).
// MODE 0: QKV fused (N=3072); Q,K -> [b][h][s][64]; V -> [b][h][64][s].
// MODE 1: out-proj (N=1024): OF[m][n] = C + b0[n]  (fp32)
template<int MODE>
__global__ __launch_bounds__(256, 3) void gemm_bt(
    const u16* __restrict__ A, const u16* __restrict__ B,
    const float* __restrict__ b0, const float* __restrict__ b1, const float* __restrict__ b2,
    u16* __restrict__ O0, u16* __restrict__ O1, u16* __restrict__ O2,
    float* __restrict__ OF)
{
    constexpr int K = 1024;
    constexpr int NBLK = (MODE == 0) ? 24 : 8;     // n-blocks per row
    constexpr int CPX  = (MODE == 0) ? 192 : 64;   // nwg / 8
    __shared__ __align__(16) u16 As[128 * 64];
    __shared__ __align__(16) u16 Bs[128 * 64];
    const int tid = threadIdx.x;
    const int wave = tid >> 6, lane = tid & 63;
    const int lin = blockIdx.y * (int)gridDim.x + blockIdx.x;   // dispatch order
    const int nl = (lin & 7) * CPX + (lin >> 3);                // bijective remap
    const int m0 = (nl / NBLK) * 128, n0 = (nl % NBLK) * 128;
    const int wm = (wave >> 1) * 64, wn = (wave & 1) * 64;
    const int fr = lane & 15, fg = lane >> 4;

    f32x4 acc[4][4] = {};

    // staging: 8 rows per ASYNC16 instr (8 lanes x 16B = 128B row)
    const int srow = lane >> 3;
    const int sw = (((lane & 7) ^ srow) << 4);   // pre-swizzled byte offset in row
    // fragment-read byte cols (swizzled), per half
    const int rdo0 = (fg * 16) ^ ((fr & 7) << 4);
    const int rdo1 = (64 + fg * 16) ^ ((fr & 7) << 4);

    auto STAGE = [&](int kt) {
        #pragma unroll
        for (int j = 0; j < 4; ++j) {
            const int row = wave * 32 + j * 8;
            ASYNC16((const char*)(A + (size_t)(m0 + row + srow) * K + kt) + sw,
                    (char*)As + row * 128);
            ASYNC16((const char*)(B + (size_t)(n0 + row + srow) * K + kt) + sw,
                    (char*)Bs + row * 128);
        }
    };

    STAGE(0);
    for (int kt = 0; kt < K; kt += 64) {
        __syncthreads();                    // tile kt staged (vmcnt drained)
        bf16x8 af[2][4], bfv[2][4];
        #pragma unroll
        for (int half = 0; half < 2; ++half) {
            const int co = half ? rdo1 : rdo0;
            #pragma unroll
            for (int i = 0; i < 4; ++i) af[half][i]  = ld8((const char*)As + (wm + i * 16 + fr) * 128 + co);
            #pragma unroll
            for (int j = 0; j < 4; ++j) bfv[half][j] = ld8((const char*)Bs + (wn + j * 16 + fr) * 128 + co);
        }
        __syncthreads();                    // all waves' LDS reads done
        if (kt + 64 < K) STAGE(kt + 64);    // prefetch overlaps MFMAs below
        #pragma unroll
        for (int half = 0; half < 2; ++half)
            #pragma unroll
            for (int i = 0; i < 4; ++i)
                #pragma unroll
                for (int j = 0; j < 4; ++j)
                    acc[i][j] = __builtin_amdgcn_mfma_f32_16x16x32_bf16(af[half][i], bfv[half][j], acc[i][j], 0, 0, 0);
    }

    if constexpr (MODE == 0) {
        const float QSCALE = 0.125f * 1.44269504f;   // 1/sqrt(64) * log2(e)
        #pragma unroll
        for (int j = 0; j < 4; ++j) {
            const int n = n0 + wn + j * 16 + fr;
            const int sel = n >> 10;          // 0=Q 1=K 2=V (uniform per fragment)
            const int w = n & 1023;
            const float bb = (sel == 0 ? b0 : sel == 1 ? b1 : b2)[w];
            const int h = w >> 6, d = w & 63;
            if (sel == 2) {
                // V transposed: Vt[(bi*16+h)*64 + d][s], s-consecutive -> u16x4
                #pragma unroll
                for (int i = 0; i < 4; ++i) {
                    const int m = m0 + wm + i * 16 + fg * 4;   // s base (4-aligned)
                    u16x4 st;
                    #pragma unroll
                    for (int r = 0; r < 4; ++r) st[r] = f2bf(acc[i][j][r] + bb);
                    *(u16x4*)&O2[((size_t)(((m >> 11) * 16 + h) * 64 + d)) * 2048 + (m & 2047)] = st;
                }
            } else {
                const float scale = (sel == 0) ? QSCALE : 1.0f;
                u16* const dst = (sel == 0 ? O0 : O1);
                #pragma unroll
                for (int i = 0; i < 4; ++i) {
                    #pragma unroll
                    for (int r = 0; r < 4; ++r) {
                        const int m = m0 + wm + i * 16 + fg * 4 + r;
                        dst[(((size_t)((m >> 11) * 16 + h) * 2048 + (m & 2047)) << 6) + d] =
                            f2bf((acc[i][j][r] + bb) * scale);
                    }
                }
            }
        }
    } else {
        #pragma unroll
        for (int j = 0; j < 4; ++j) {
            const int n = n0 + wn + j * 16 + fr;
            const float bb = b0[n];
            #pragma unroll
            for (int i = 0; i < 4; ++i) {
                #pragma unroll
                for (int r = 0; r < 4; ++r) {
                    const int m = m0 + wm + i * 16 + fg * 4 + r;
                    OF[(size_t)m * 1024 + n] = acc[i][j][r] + bb;
                }
            }
        }
    }
}

// ---------------- attention kv-loop body, QROWS=64/wave -----------------------
// K/V LDS-staged (fetch-once shared by 4 waves); K/V fragment reads are
// qs-invariant -> 64 q-rows/wave amortizes each ds_read over 2x the MFMA work.
template<bool MASKED>
__device__ __forceinline__ void kv_loop(
    char* smem, const u16* __restrict__ Kbh, const u16* __restrict__ Vtbh,
    const float* __restrict__ mrow, int wave, int fg, int a0, int a1, int t0,
    int srow, int scb, bf16x8 (&qf)[4][2], f32x4 (&o)[4][4], f32x4 (&den)[4],
    const f32x4& FZ, const bf16x8& ONES)
{
    auto STAGE = [&](int buf, int kv0) {
        #pragma unroll
        for (int j = 0; j < 2; ++j) {
            const int r0 = wave * 16 + j * 8;
            const int row = r0 + srow;
            const int sw = scb ^ ((row & 7) << 4);
            ASYNC16((const char*)(Kbh + (size_t)(kv0 + row) * 64) + sw,
                    smem + buf * 8192 + r0 * 128);
            ASYNC16((const char*)(Vtbh + (size_t)row * 2048 + kv0) + sw,
                    smem + 16384 + buf * 8192 + r0 * 128);
        }
    };

    STAGE(0, t0 * 64);
    for (int it = 0; it < 32; it += 2) {
        #pragma unroll
        for (int half = 0; half < 2; ++half) {
            const int tile = (t0 + it + half) & 31;
            const int kv = tile * 64;
            const int kb = half * 8192;            // compile-time dbuf bases
            const int vb = 16384 + half * 8192;
            __syncthreads();                        // buf[half] staged
            if (it + half < 31) STAGE(half ^ 1, ((tile + 1) & 31) * 64);

            float4 mv[4];
            if (MASKED) {
                #pragma unroll
                for (int nj = 0; nj < 4; ++nj)
                    mv[nj] = *(const float4*)(mrow + kv + nj * 16 + fg * 4);
            }

            // per 32-key half: QK -> softmax -> in-reg transpose -> PV
            #pragma unroll
            for (int hh = 0; hh < 2; ++hh) {
                const int aK = hh ? a1 : a0;        // V frag byte-half for this hh
                f32x4 s[2][4];
                #pragma unroll
                for (int njl = 0; njl < 2; ++njl) {
                    const int nj = hh * 2 + njl;
                    bf16x8 k0 = ld8(smem + kb + nj * 2048 + a0);
                    bf16x8 k1 = ld8(smem + kb + nj * 2048 + a1);
                    __builtin_amdgcn_s_setprio(1);
                    #pragma unroll
                    for (int qs = 0; qs < 4; ++qs) {
                        f32x4 z = __builtin_amdgcn_mfma_f32_16x16x32_bf16(k0, qf[qs][0], FZ, 0, 0, 0);
                        s[njl][qs] = __builtin_amdgcn_mfma_f32_16x16x32_bf16(k1, qf[qs][1], z, 0, 0, 0);
                    }
                    __builtin_amdgcn_s_setprio(0);
                }
                // softmax in place: p = exp2(s) [* mask]   (raw-rate v_exp_f32)
                #pragma unroll
                for (int njl = 0; njl < 2; ++njl) {
                    const int nj = hh * 2 + njl;
                    #pragma unroll
                    for (int qs = 0; qs < 4; ++qs)
                        #pragma unroll
                        for (int r = 0; r < 4; ++r) {
                            float p = EXP2(s[njl][qs][r]);
                            if (MASKED) p *= mv[nj][r];
                            s[njl][qs][r] = p;
                        }
                }
                // pack + 4x4 cross-lane transpose -> PV B-operand fragments
                bf16x8 pa[4];
                #pragma unroll
                for (int qs = 0; qs < 4; ++qs) {
                    u32 m0, m1, m2, m3;   // word (W1=njl, W0=r-pair)
                    asm("v_cvt_pk_bf16_f32 %0, %1, %2" : "=v"(m0) : "v"(s[0][qs][0]), "v"(s[0][qs][1]));
                    asm("v_cvt_pk_bf16_f32 %0, %1, %2" : "=v"(m1) : "v"(s[0][qs][2]), "v"(s[0][qs][3]));
                    asm("v_cvt_pk_bf16_f32 %0, %1, %2" : "=v"(m2) : "v"(s[1][qs][0]), "v"(s[1][qs][1]));
                    asm("v_cvt_pk_bf16_f32 %0, %1, %2" : "=v"(m3) : "v"(s[1][qs][2]), "v"(s[1][qs][3]));
                    // step 1: swap(L5, W1); step 2: swap(L4, W1)
                    asm("v_permlane32_swap_b32 %0, %1" : "+v"(m0), "+v"(m2));
                    asm("v_permlane32_swap_b32 %0, %1" : "+v"(m1), "+v"(m3));
                    asm("v_permlane16_swap_b32 %0, %1" : "+v"(m0), "+v"(m2));
                    asm("v_permlane16_swap_b32 %0, %1" : "+v"(m1), "+v"(m3));
                    pa[qs] = __builtin_bit_cast(bf16x8, u32x4{m0, m1, m2, m3});
                }

                // PV + MFMA denominator (row-sum with ONES A-operand)
                __builtin_amdgcn_s_setprio(1);
                #pragma unroll
                for (int qs = 0; qs < 4; ++qs)
                    den[qs] = __builtin_amdgcn_mfma_f32_16x16x32_bf16(ONES, pa[qs], den[qs], 0, 0, 0);
                #pragma unroll
                for (int dj = 0; dj < 4; ++dj) {
                    bf16x8 v = ld8(smem + vb + dj * 2048 + aK);
                    #pragma unroll
                    for (int qs = 0; qs < 4; ++qs)
                        o[dj][qs] = __builtin_amdgcn_mfma_f32_16x16x32_bf16(v, pa[qs], o[dj][qs], 0, 0, 0);
                }
                __builtin_amdgcn_s_setprio(0);
            }
        }
    }
}

// ---------------- flash attention: in-reg P, QROWS=64, mask fast-path ---------
// Q [bh][s][64] pre-scaled by 0.125*log2e, K [bh][s][64], Vt [bh][64][s],
// masks [b][s] fp32 (binary), out X2 [b][s][h*64+d] bf16.
// 4 waves x 64 q-rows = 256 q-rows/block; grid 512 (2 blocks/CU).
__global__ __launch_bounds__(256, 2) void attn_fwd(
    const u16* __restrict__ Qg, const u16* __restrict__ Kg, const u16* __restrict__ Vt,
    const float* __restrict__ masks, u16* __restrict__ X2)
{
    __shared__ __align__(16) char smem[32768];
    const int tid = threadIdx.x;
    const int wave = tid >> 6, lane = tid & 63;

    // bijective XCD swizzle: 512 wgs / 8 XCDs -> 64 contiguous wgs (8 bh) per XCD
    const int bidL = blockIdx.x;
    const int wg = ((bidL & 7) << 6) | (bidL >> 3);
    const int bh = wg >> 3;                        // 8 q-blocks per bh
    const int q0 = (wg & 7) * 256 + wave * 64;
    const int b = bh >> 4, h = bh & 15;
    const int fr = lane & 15, fg = lane >> 4;
    const int swz = (fr & 7) << 4;

    // loop-invariant LDS byte addresses
    const int a0 = fr * 128 + ((fg * 16) ^ swz);          // frag low 64B (k/d 0-31)
    const int a1 = fr * 128 + ((64 + fg * 16) ^ swz);     // frag high 64B

    const u16* const Kbh  = Kg + (size_t)bh * 2048 * 64;
    const u16* const Vtbh = Vt + (size_t)bh * 64 * 2048;
    const float* mrow = masks + b * 2048;

    // Q fragments (B-operand): 4 strips of 16 rows
    bf16x8 qf[4][2];
    #pragma unroll
    for (int qs = 0; qs < 4; ++qs) {
        const u16* qp = Qg + ((size_t)bh * 2048 + q0 + qs * 16 + fr) * 64 + fg * 8;
        qf[qs][0] = ld8(qp);
        qf[qs][1] = ld8(qp + 32);
    }

    // wave-uniform all-ones mask check (64 lanes x 8 float4 = 2048 values)
    bool ok = true;
    {
        const float4* mp = (const float4*)mrow;
        #pragma unroll
        for (int i = 0; i < 8; ++i) {
            float4 m = mp[lane + i * 64];
            ok = ok && (m.x == 1.0f) && (m.y == 1.0f) && (m.z == 1.0f) && (m.w == 1.0f);
        }
        ok = __all(ok);
    }

    f32x4 o[4][4] = {};                 // o[dj][qs]: d=dj*16+fg*4+r, q=qs*16+fr
    f32x4 den[4] = {};                  // softmax denominator (all 4 rows identical)
    const f32x4 FZ = {0.f, 0.f, 0.f, 0.f};                 // shared zero C-operand
    const u16x8 ONE_BITS = {0x3F80,0x3F80,0x3F80,0x3F80,0x3F80,0x3F80,0x3F80,0x3F80};
    const bf16x8 ONES = __builtin_bit_cast(bf16x8, ONE_BITS); // bf16 1.0 x8

    const int srow = lane >> 3;
    const int scb = (lane & 7) * 16;

    // co-resident blocks (p, p+256) start 16 tiles apart (key order commutes:
    // no-max softmax + linear denominator) -> pipe bursts interleave
    const int t0 = (((bidL >> 8) & 1) << 4);

    if (ok)
        kv_loop<false>(smem, Kbh, Vtbh, mrow, wave, fg, a0, a1, t0, srow, scb,
                       qf, o, den, FZ, ONES);
    else
        kv_loop<true>(smem, Kbh, Vtbh, mrow, wave, fg, a0, a1, t0, srow, scb,
                      qf, o, den, FZ, ONES);

    // normalize + store (den available in every lane; no cross-lane reduce)
    #pragma unroll
    for (int qs = 0; qs < 4; ++qs) {
        const float inv = 1.0f / den[qs][0];
        const int q = q0 + qs * 16 + fr;
        u16* dst = X2 + ((size_t)(b * 2048 + q)) * 1024 + h * 64 + fg * 4;
        #pragma unroll
        for (int dj = 0; dj < 4; ++dj) {
            u16x4 st;
            #pragma unroll
            for (int r = 0; r < 4; ++r) st[r] = f2bf(o[dj][qs][r] * inv);
            *(u16x4*)(dst + dj * 16) = st;
        }
    }
}

// ---------------- launch ----------------
extern "C" void kernel_launch(void* const* d_in, const int* in_sizes, int n_in,
                              void* d_out, int out_size, void* d_ws, size_t ws_size,
                              hipStream_t stream) {
    const float* query = (const float*)d_in[0];
    const float* masks = (const float*)d_in[1];
    const float* Wq = (const float*)d_in[2];
    const float* bq = (const float*)d_in[3];
    const float* Wk = (const float*)d_in[4];
    const float* bk = (const float*)d_in[5];
    const float* Wv = (const float*)d_in[6];
    const float* bv = (const float*)d_in[7];
    const float* Wo = (const float*)d_in[8];
    const float* bo = (const float*)d_in[9];
    float* out = (float*)d_out;

    // workspace (72 MB):
    //  [ 0,16M): Xb (bf16 query)  -> reused as X2 (attn out) after QKV GEMM
    //  [16,22M): Wcat  [22,24M): Wob
    //  [24,40M): Qg   [40,56M): Kg   [56,72M): Vt (written transposed by GEMM)
    char* ws = (char*)d_ws;
    u16* Xb   = (u16*)(ws);
    u16* Wcat = (u16*)(ws + (16u << 20));
    u16* Wob  = (u16*)(ws + (22u << 20));
    u16* Qg   = (u16*)(ws + (24u << 20));
    u16* Kg   = (u16*)(ws + (40u << 20));
    u16* Vt   = (u16*)(ws + (56u << 20));
    u16* X2   = Xb;   // Xb dead after QKV GEMM

    cvt_all<<<12288, 256, 0, stream>>>(query, Wq, Wk, Wv, Wo, Xb, Wcat, Wob);
    gemm_bt<0><<<dim3(24, 64), 256, 0, stream>>>(Xb, Wcat, bq, bk, bv, Qg, Kg, Vt, nullptr);
    attn_fwd<<<512, 256, 0, stream>>>(Qg, Kg, Vt, masks, X2);
    gemm_bt<1><<<dim3(8, 64), 256, 0, stream>>>(X2, Wob, bo, nullptr, nullptr, nullptr,
                                                nullptr, nullptr, out);
}

// Round 18
// 163.609 us; speedup vs baseline: 1.0676x; 1.0169x over previous
//
#include <hip/hip_runtime.h>

typedef unsigned short u16;
typedef unsigned int u32;
typedef u16 u16x4 __attribute__((ext_vector_type(4)));
typedef u16 u16x8 __attribute__((ext_vector_type(8)));
typedef u32 u32x4 __attribute__((ext_vector_type(4)));
typedef __bf16 bf16x8 __attribute__((ext_vector_type(8)));
typedef float f32x4 __attribute__((ext_vector_type(4)));

#define GPTR(p) (const __attribute__((address_space(1))) void*)(p)
#define LPTR(p) (__attribute__((address_space(3))) void*)(p)
// async global->LDS, 16B per lane; LDS dest = wave-uniform base + lane*16
#define ASYNC16(g, l) __builtin_amdgcn_global_load_lds(GPTR(g), LPTR(l), 16, 0, 0)

// raw v_exp_f32 (no denormal-range fixup; inputs here are |x| < 40)
#if __has_builtin(__builtin_amdgcn_exp2f)
#define EXP2(x) __builtin_amdgcn_exp2f(x)
#else
#define EXP2(x) __builtin_exp2f(x)
#endif

// fp32 -> bf16 RTNE (epilogue / non-hot paths)
__device__ __forceinline__ u16 f2bf(float f) {
    u32 u = __builtin_bit_cast(u32, f);
    return (u16)((u + 0x7fffu + ((u >> 16) & 1u)) >> 16);
}
__device__ __forceinline__ bf16x8 ld8(const void* p) {
    return __builtin_bit_cast(bf16x8, *(const u16x8*)p);
}

// ---------------- fused fp32 -> bf16 conversion (single dispatch) -------------
// blocks [0,8192): query -> Xb;  [8192,+1024) each: Wq,Wk,Wv -> Wcat, Wo -> Wob
__global__ void cvt_all(const float* __restrict__ q,
                        const float* __restrict__ wq, const float* __restrict__ wk,
                        const float* __restrict__ wv, const float* __restrict__ wo,
                        u16* __restrict__ xb, u16* __restrict__ wcat, u16* __restrict__ wob) {
    const int blk = blockIdx.x;
    const float* src;
    u16* dst;
    size_t base;
    if (blk < 8192) {
        src = q; dst = xb; base = (size_t)blk * 256;
    } else {
        const int t = blk - 8192;
        const int w = t >> 10;
        base = (size_t)(t & 1023) * 256;
        src = (w == 0) ? wq : (w == 1) ? wk : (w == 2) ? wv : wo;
        dst = (w == 0) ? wcat : (w == 1) ? wcat + 1024 * 1024
            : (w == 2) ? wcat + 2 * 1024 * 1024 : wob;
    }
    const size_t i = base + threadIdx.x;
    float4 v = ((const float4*)src)[i];
    ushort4 o4;
    o4.x = f2bf(v.x); o4.y = f2bf(v.y); o4.z = f2bf(v.z); o4.w = f2bf(v.w);
    ((ushort4*)dst)[i] = o4;
}

// ---------------- GEMM: C[m][n] = sum_k A[m][k]*B[n][k]  (B^T input) ----------
// BK=64, XOR-swizzled LDS tiles (128B rows), XCD-chunked block swizzle.
// Per K-step: barrier -> ds_read ALL 16 b128 to regs -> barrier -> issue NEXT
// tile's ASYNC16 -> 32 MFMAs (prefetch flies under them).
// MODE 0: QKV fused (N=3072); Q,K -> [b][h][s][64]; V -> [b][h][64][s].
// MODE 1: out-proj (N=1024): OF[m][n] = C + b0[n]  (fp32)
template<int MODE>
__global__ __launch_bounds__(256, 3) void gemm_bt(
    const u16* __restrict__ A, const u16* __restrict__ B,
    const float* __restrict__ b0, const float* __restrict__ b1, const float* __restrict__ b2,
    u16* __restrict__ O0, u16* __restrict__ O1, u16* __restrict__ O2,
    float* __restrict__ OF)
{
    constexpr int K = 1024;
    constexpr int NBLK = (MODE == 0) ? 24 : 8;     // n-blocks per row
    constexpr int CPX  = (MODE == 0) ? 192 : 64;   // nwg / 8
    __shared__ __align__(16) u16 As[128 * 64];
    __shared__ __align__(16) u16 Bs[128 * 64];
    const int tid = threadIdx.x;
    const int wave = tid >> 6, lane = tid & 63;
    const int lin = blockIdx.y * (int)gridDim.x + blockIdx.x;   // dispatch order
    const int nl = (lin & 7) * CPX + (lin >> 3);                // bijective remap
    const int m0 = (nl / NBLK) * 128, n0 = (nl % NBLK) * 128;
    const int wm = (wave >> 1) * 64, wn = (wave & 1) * 64;
    const int fr = lane & 15, fg = lane >> 4;

    f32x4 acc[4][4] = {};

    const int srow = lane >> 3;
    const int sw = (((lane & 7) ^ srow) << 4);   // pre-swizzled byte offset in row
    const int rdo0 = (fg * 16) ^ ((fr & 7) << 4);
    const int rdo1 = (64 + fg * 16) ^ ((fr & 7) << 4);

    auto STAGE = [&](int kt) {
        #pragma unroll
        for (int j = 0; j < 4; ++j) {
            const int row = wave * 32 + j * 8;
            ASYNC16((const char*)(A + (size_t)(m0 + row + srow) * K + kt) + sw,
                    (char*)As + row * 128);
            ASYNC16((const char*)(B + (size_t)(n0 + row + srow) * K + kt) + sw,
                    (char*)Bs + row * 128);
        }
    };

    STAGE(0);
    for (int kt = 0; kt < K; kt += 64) {
        __syncthreads();                    // tile kt staged (vmcnt drained)
        bf16x8 af[2][4], bfv[2][4];
        #pragma unroll
        for (int half = 0; half < 2; ++half) {
            const int co = half ? rdo1 : rdo0;
            #pragma unroll
            for (int i = 0; i < 4; ++i) af[half][i]  = ld8((const char*)As + (wm + i * 16 + fr) * 128 + co);
            #pragma unroll
            for (int j = 0; j < 4; ++j) bfv[half][j] = ld8((const char*)Bs + (wn + j * 16 + fr) * 128 + co);
        }
        __syncthreads();                    // all waves' LDS reads done
        if (kt + 64 < K) STAGE(kt + 64);    // prefetch overlaps MFMAs below
        #pragma unroll
        for (int half = 0; half < 2; ++half)
            #pragma unroll
            for (int i = 0; i < 4; ++i)
                #pragma unroll
                for (int j = 0; j < 4; ++j)
                    acc[i][j] = __builtin_amdgcn_mfma_f32_16x16x32_bf16(af[half][i], bfv[half][j], acc[i][j], 0, 0, 0);
    }

    if constexpr (MODE == 0) {
        const float QSCALE = 0.125f * 1.44269504f;   // 1/sqrt(64) * log2(e)
        #pragma unroll
        for (int j = 0; j < 4; ++j) {
            const int n = n0 + wn + j * 16 + fr;
            const int sel = n >> 10;          // 0=Q 1=K 2=V (uniform per fragment)
            const int w = n & 1023;
            const float bb = (sel == 0 ? b0 : sel == 1 ? b1 : b2)[w];
            const int h = w >> 6, d = w & 63;
            if (sel == 2) {
                // V transposed: Vt[(bi*16+h)*64 + d][s], s-consecutive -> u16x4
                #pragma unroll
                for (int i = 0; i < 4; ++i) {
                    const int m = m0 + wm + i * 16 + fg * 4;   // s base (4-aligned)
                    u16x4 st;
                    #pragma unroll
                    for (int r = 0; r < 4; ++r) st[r] = f2bf(acc[i][j][r] + bb);
                    *(u16x4*)&O2[((size_t)(((m >> 11) * 16 + h) * 64 + d)) * 2048 + (m & 2047)] = st;
                }
            } else {
                const float scale = (sel == 0) ? QSCALE : 1.0f;
                u16* const dst = (sel == 0 ? O0 : O1);
                #pragma unroll
                for (int i = 0; i < 4; ++i) {
                    #pragma unroll
                    for (int r = 0; r < 4; ++r) {
                        const int m = m0 + wm + i * 16 + fg * 4 + r;
                        dst[(((size_t)((m >> 11) * 16 + h) * 2048 + (m & 2047)) << 6) + d] =
                            f2bf((acc[i][j][r] + bb) * scale);
                    }
                }
            }
        }
    } else {
        #pragma unroll
        for (int j = 0; j < 4; ++j) {
            const int n = n0 + wn + j * 16 + fr;
            const float bb = b0[n];
            #pragma unroll
            for (int i = 0; i < 4; ++i) {
                #pragma unroll
                for (int r = 0; r < 4; ++r) {
                    const int m = m0 + wm + i * 16 + fg * 4 + r;
                    OF[(size_t)m * 1024 + n] = acc[i][j][r] + bb;
                }
            }
        }
    }
}

// ---------------- attention kv-loop body, QROWS=64/wave, KVBLK=128 ------------
// 128-key tiles halve barrier count (16 vs 32) and give each staging burst 4
// compute phases of cover.  smem 64KB: K dbuf [0,32K) (2 x 128x128B tiles),
// V dbuf [32K,64K) (2 x 64x256B tiles, swizzle col^((row&15)<<4)).
template<bool MASKED>
__device__ __forceinline__ void kv_loop(
    char* smem, const u16* __restrict__ Kbh, const u16* __restrict__ Vtbh,
    const float* __restrict__ mrow, int wave, int lane, int fg, int a0, int a1,
    int t0, bf16x8 (&qf)[4][2], f32x4 (&o)[4][4], f32x4 (&den)[4],
    const f32x4& FZ, const bf16x8& ONES)
{
    const int srow = lane >> 3;          // K staging: 8 rows/instr
    const int scb = (lane & 7) * 16;
    const int srowV = lane >> 4;         // V staging: 4 rows/instr (256B rows)
    const int scbV = (lane & 15) * 16;
    const int fr = lane & 15;

    auto STAGE = [&](int buf, int kv0) {
        #pragma unroll
        for (int j = 0; j < 4; ++j) {    // K: 128 rows x 128B
            const int r0 = wave * 32 + j * 8;
            const int row = r0 + srow;
            const int sw = scb ^ ((row & 7) << 4);
            ASYNC16((const char*)(Kbh + (size_t)(kv0 + row) * 64) + sw,
                    smem + buf * 16384 + r0 * 128);
        }
        #pragma unroll
        for (int j = 0; j < 4; ++j) {    // V: 64 rows x 256B
            const int r0 = wave * 16 + j * 4;
            const int row = r0 + srowV;
            const int sw = scbV ^ ((row & 15) << 4);
            ASYNC16((const char*)(Vtbh + (size_t)row * 2048 + kv0) + sw,
                    smem + 32768 + buf * 16384 + r0 * 256);
        }
    };

    const int vswz = fr << 4;            // V read swizzle: (row&15)==fr

    STAGE(0, t0 * 128);
    for (int it = 0; it < 16; it += 2) {
        #pragma unroll
        for (int half = 0; half < 2; ++half) {
            const int tile = (t0 + it + half) & 15;
            const int kv = tile * 128;
            const int kb = half * 16384;             // compile-time dbuf bases
            const int vb = 32768 + half * 16384;
            __syncthreads();                          // buf[half] staged
            if (it + half < 15) STAGE(half ^ 1, ((tile + 1) & 15) * 128);

            // 4 phases of 32 keys: QK -> softmax -> in-reg transpose -> PV
            #pragma unroll
            for (int hh = 0; hh < 4; ++hh) {
                float4 mv[2];
                if (MASKED) {
                    #pragma unroll
                    for (int njl = 0; njl < 2; ++njl)
                        mv[njl] = *(const float4*)(mrow + kv + (hh * 2 + njl) * 16 + fg * 4);
                }
                f32x4 s[2][4];
                #pragma unroll
                for (int njl = 0; njl < 2; ++njl) {
                    const int nj = hh * 2 + njl;
                    bf16x8 k0 = ld8(smem + kb + nj * 2048 + a0);
                    bf16x8 k1 = ld8(smem + kb + nj * 2048 + a1);
                    __builtin_amdgcn_s_setprio(1);
                    #pragma unroll
                    for (int qs = 0; qs < 4; ++qs) {
                        f32x4 z = __builtin_amdgcn_mfma_f32_16x16x32_bf16(k0, qf[qs][0], FZ, 0, 0, 0);
                        s[njl][qs] = __builtin_amdgcn_mfma_f32_16x16x32_bf16(k1, qf[qs][1], z, 0, 0, 0);
                    }
                    __builtin_amdgcn_s_setprio(0);
                }
                // softmax in place: p = exp2(s) [* mask]   (raw-rate v_exp_f32)
                #pragma unroll
                for (int njl = 0; njl < 2; ++njl)
                    #pragma unroll
                    for (int qs = 0; qs < 4; ++qs)
                        #pragma unroll
                        for (int r = 0; r < 4; ++r) {
                            float p = EXP2(s[njl][qs][r]);
                            if (MASKED) p *= mv[njl][r];
                            s[njl][qs][r] = p;
                        }
                // pack + 4x4 cross-lane transpose -> PV B-operand fragments
                bf16x8 pa[4];
                #pragma unroll
                for (int qs = 0; qs < 4; ++qs) {
                    u32 m0, m1, m2, m3;   // word (W1=njl, W0=r-pair)
                    asm("v_cvt_pk_bf16_f32 %0, %1, %2" : "=v"(m0) : "v"(s[0][qs][0]), "v"(s[0][qs][1]));
                    asm("v_cvt_pk_bf16_f32 %0, %1, %2" : "=v"(m1) : "v"(s[0][qs][2]), "v"(s[0][qs][3]));
                    asm("v_cvt_pk_bf16_f32 %0, %1, %2" : "=v"(m2) : "v"(s[1][qs][0]), "v"(s[1][qs][1]));
                    asm("v_cvt_pk_bf16_f32 %0, %1, %2" : "=v"(m3) : "v"(s[1][qs][2]), "v"(s[1][qs][3]));
                    // step 1: swap(L5, W1); step 2: swap(L4, W1)
                    asm("v_permlane32_swap_b32 %0, %1" : "+v"(m0), "+v"(m2));
                    asm("v_permlane32_swap_b32 %0, %1" : "+v"(m1), "+v"(m3));
                    asm("v_permlane16_swap_b32 %0, %1" : "+v"(m0), "+v"(m2));
                    asm("v_permlane16_swap_b32 %0, %1" : "+v"(m1), "+v"(m3));
                    pa[qs] = __builtin_bit_cast(bf16x8, u32x4{m0, m1, m2, m3});
                }

                // PV + MFMA denominator (row-sum with ONES A-operand)
                __builtin_amdgcn_s_setprio(1);
                #pragma unroll
                for (int qs = 0; qs < 4; ++qs)
                    den[qs] = __builtin_amdgcn_mfma_f32_16x16x32_bf16(ONES, pa[qs], den[qs], 0, 0, 0);
                #pragma unroll
                for (int dj = 0; dj < 4; ++dj) {
                    // V row = dj*16+fr (256B), keys hh*32 + fg*8..+7
                    bf16x8 v = ld8(smem + vb + (dj * 16 + fr) * 256 + ((hh * 64 + fg * 16) ^ vswz));
                    #pragma unroll
                    for (int qs = 0; qs < 4; ++qs)
                        o[dj][qs] = __builtin_amdgcn_mfma_f32_16x16x32_bf16(v, pa[qs], o[dj][qs], 0, 0, 0);
                }
                __builtin_amdgcn_s_setprio(0);
            }
        }
    }
}

// ---------------- flash attention: in-reg P, QROWS=64, KVBLK=128 --------------
// Q [bh][s][64] pre-scaled by 0.125*log2e, K [bh][s][64], Vt [bh][64][s],
// masks [b][s] fp32 (binary), out X2 [b][s][h*64+d] bf16.
// 4 waves x 64 q-rows = 256 q-rows/block; grid 512 (2 blocks/CU).
__global__ __launch_bounds__(256, 2) void attn_fwd(
    const u16* __restrict__ Qg, const u16* __restrict__ Kg, const u16* __restrict__ Vt,
    const float* __restrict__ masks, u16* __restrict__ X2)
{
    __shared__ __align__(16) char smem[65536];
    const int tid = threadIdx.x;
    const int wave = tid >> 6, lane = tid & 63;

    // bijective XCD swizzle: 512 wgs / 8 XCDs -> 64 contiguous wgs (8 bh) per XCD
    const int bidL = blockIdx.x;
    const int wg = ((bidL & 7) << 6) | (bidL >> 3);
    const int bh = wg >> 3;                        // 8 q-blocks per bh
    const int q0 = (wg & 7) * 256 + wave * 64;
    const int b = bh >> 4, h = bh & 15;
    const int fr = lane & 15, fg = lane >> 4;
    const int swz = (fr & 7) << 4;

    // loop-invariant LDS byte addresses (K reads, 128B rows)
    const int a0 = fr * 128 + ((fg * 16) ^ swz);          // frag low 64B (d 0-31)
    const int a1 = fr * 128 + ((64 + fg * 16) ^ swz);     // frag high 64B

    const u16* const Kbh  = Kg + (size_t)bh * 2048 * 64;
    const u16* const Vtbh = Vt + (size_t)bh * 64 * 2048;
    const float* mrow = masks + b * 2048;

    // Q fragments (B-operand): 4 strips of 16 rows
    bf16x8 qf[4][2];
    #pragma unroll
    for (int qs = 0; qs < 4; ++qs) {
        const u16* qp = Qg + ((size_t)bh * 2048 + q0 + qs * 16 + fr) * 64 + fg * 8;
        qf[qs][0] = ld8(qp);
        qf[qs][1] = ld8(qp + 32);
    }

    // wave-uniform all-ones mask check (64 lanes x 8 float4 = 2048 values)
    bool ok = true;
    {
        const float4* mp = (const float4*)mrow;
        #pragma unroll
        for (int i = 0; i < 8; ++i) {
            float4 m = mp[lane + i * 64];
            ok = ok && (m.x == 1.0f) && (m.y == 1.0f) && (m.z == 1.0f) && (m.w == 1.0f);
        }
        ok = __all(ok);
    }

    f32x4 o[4][4] = {};                 // o[dj][qs]: d=dj*16+fg*4+r, q=qs*16+fr
    f32x4 den[4] = {};                  // softmax denominator (all 4 rows identical)
    const f32x4 FZ = {0.f, 0.f, 0.f, 0.f};                 // shared zero C-operand
    const u16x8 ONE_BITS = {0x3F80,0x3F80,0x3F80,0x3F80,0x3F80,0x3F80,0x3F80,0x3F80};
    const bf16x8 ONES = __builtin_bit_cast(bf16x8, ONE_BITS); // bf16 1.0 x8

    // co-resident blocks (p, p+256) start 8 of 16 tiles apart (key order
    // commutes: no-max softmax + linear denominator)
    const int t0 = (((bidL >> 8) & 1) << 3);

    if (ok)
        kv_loop<false>(smem, Kbh, Vtbh, mrow, wave, lane, fg, a0, a1, t0,
                       qf, o, den, FZ, ONES);
    else
        kv_loop<true>(smem, Kbh, Vtbh, mrow, wave, lane, fg, a0, a1, t0,
                      qf, o, den, FZ, ONES);

    // normalize + store (den available in every lane; no cross-lane reduce)
    #pragma unroll
    for (int qs = 0; qs < 4; ++qs) {
        const float inv = 1.0f / den[qs][0];
        const int q = q0 + qs * 16 + fr;
        u16* dst = X2 + ((size_t)(b * 2048 + q)) * 1024 + h * 64 + fg * 4;
        #pragma unroll
        for (int dj = 0; dj < 4; ++dj) {
            u16x4 st;
            #pragma unroll
            for (int r = 0; r < 4; ++r) st[r] = f2bf(o[dj][qs][r] * inv);
            *(u16x4*)(dst + dj * 16) = st;
        }
    }
}

// ---------------- launch ----------------
extern "C" void kernel_launch(void* const* d_in, const int* in_sizes, int n_in,
                              void* d_out, int out_size, void* d_ws, size_t ws_size,
                              hipStream_t stream) {
    const float* query = (const float*)d_in[0];
    const float* masks = (const float*)d_in[1];
    const float* Wq = (const float*)d_in[2];
    const float* bq = (const float*)d_in[3];
    const float* Wk = (const float*)d_in[4];
    const float* bk = (const float*)d_in[5];
    const float* Wv = (const float*)d_in[6];
    const float* bv = (const float*)d_in[7];
    const float* Wo = (const float*)d_in[8];
    const float* bo = (const float*)d_in[9];
    float* out = (float*)d_out;

    // workspace (72 MB):
    //  [ 0,16M): Xb (bf16 query)  -> reused as X2 (attn out) after QKV GEMM
    //  [16,22M): Wcat  [22,24M): Wob
    //  [24,40M): Qg   [40,56M): Kg   [56,72M): Vt (written transposed by GEMM)
    char* ws = (char*)d_ws;
    u16* Xb   = (u16*)(ws);
    u16* Wcat = (u16*)(ws + (16u << 20));
    u16* Wob  = (u16*)(ws + (22u << 20));
    u16* Qg   = (u16*)(ws + (24u << 20));
    u16* Kg   = (u16*)(ws + (40u << 20));
    u16* Vt   = (u16*)(ws + (56u << 20));
    u16* X2   = Xb;   // Xb dead after QKV GEMM

    cvt_all<<<12288, 256, 0, stream>>>(query, Wq, Wk, Wv, Wo, Xb, Wcat, Wob);
    gemm_bt<0><<<dim3(24, 64), 256, 0, stream>>>(Xb, Wcat, bq, bk, bv, Qg, Kg, Vt, nullptr);
    attn_fwd<<<512, 256, 0, stream>>>(Qg, Kg, Vt, masks, X2);
    gemm_bt<1><<<dim3(8, 64), 256, 0, stream>>>(X2, Wob, bo, nullptr, nullptr, nullptr,
                                                nullptr, nullptr, out);
}